// Round 4
// baseline (377.070 us; speedup 1.0000x reference)
//
#include <hip/hip_runtime.h>
#include <hip/hip_bf16.h>

#define NSP 4096      // D*H*W
#define CH 256
#define NB 2
#define NG 8
#define CPG 32        // channels per group
#define NHD 4         // heads
#define HDIM 64       // head dim

typedef unsigned short u16;
typedef unsigned int u32;
typedef __attribute__((ext_vector_type(8))) short bf16x8;
typedef __attribute__((ext_vector_type(4))) float f32x4;

#define MFMA __builtin_amdgcn_mfma_f32_16x16x32_bf16

__device__ __forceinline__ u16 f2bf(float f) {
    u32 i = __float_as_uint(f);
    u32 r = (i + 0x7FFFu + ((i >> 16) & 1u)) >> 16;   // round-nearest-even
    return (u16)r;
}

// ---------------- fp32 -> bf16 weight conversion ----------------
__global__ __launch_bounds__(256) void wconv(const float* __restrict__ src,
                                             u16* __restrict__ dst, int n) {
    int i = (blockIdx.x * 256 + threadIdx.x) * 4;
    if (i < n) {
        float4 v = *(const float4*)(src + i);
        ushort4 o;
        o.x = f2bf(v.x); o.y = f2bf(v.y); o.z = f2bf(v.z); o.w = f2bf(v.w);
        *(ushort4*)(dst + i) = o;
    }
}

// ---------------- GroupNorm stats: one block per (b,g), fp32 input ----------------
__global__ __launch_bounds__(256) void gn_stats(const float* __restrict__ x,
                                                float* __restrict__ stats) {
    int bg = blockIdx.x;                       // 0..15 ; contiguous 32x4096 chunk
    const float* p = x + (size_t)bg * (CPG * NSP);
    float s = 0.f, ss = 0.f;
    const int nv = (CPG * NSP) / 4;
    for (int i = threadIdx.x; i < nv; i += 256) {
        float4 u = ((const float4*)p)[i];
        s += u.x + u.y + u.z + u.w;
        ss += u.x * u.x + u.y * u.y + u.z * u.z + u.w * u.w;
    }
    __shared__ float rs[256], rq[256];
    rs[threadIdx.x] = s; rq[threadIdx.x] = ss;
    __syncthreads();
    for (int st = 128; st > 0; st >>= 1) {
        if (threadIdx.x < st) { rs[threadIdx.x] += rs[threadIdx.x + st];
                                rq[threadIdx.x] += rq[threadIdx.x + st]; }
        __syncthreads();
    }
    if (threadIdx.x == 0) {
        const float cnt = (float)(CPG * NSP);
        float mean = rs[0] / cnt;
        float var  = rq[0] / cnt - mean * mean;
        stats[bg * 2]     = mean;
        stats[bg * 2 + 1] = rsqrtf(var + 1e-5f);
    }
}

// ------- GroupNorm apply + transpose: x[b][c][n] fp32 -> xnT[b][n][c] bf16 -------
// 64x64 tile. Load side: lane = channel rc (bank-spread writes), row wave-uniform.
__global__ __launch_bounds__(256) void gn_apply_t(const float* __restrict__ x,
                                                  const float* __restrict__ stats,
                                                  const float* __restrict__ w,
                                                  const float* __restrict__ b,
                                                  u16* __restrict__ xnT) {
    __shared__ u16 T[64][72];   // [n][c], pitch 144 B (16B-aligned rows)
    const int n0 = blockIdx.x * 64, c0 = blockIdx.y * 64, bb = blockIdx.z;
    const int t = threadIdx.x;
    const int rc = t & 63;          // channel within tile
    const int g  = t >> 6;          // n-chunk group of 16
    const int c  = c0 + rc;
    const int bg = bb * NG + c / CPG;
    float mean = stats[bg * 2], rstd = stats[bg * 2 + 1];
    float wf = w[c] * rstd, bv = b[c] - mean * wf;
    const float* px = x + ((size_t)bb * CH + c) * NSP + n0 + g * 16;
#pragma unroll
    for (int i = 0; i < 4; ++i) {
        float4 v = *(const float4*)(px + i * 4);
        T[g * 16 + i * 4 + 0][rc] = f2bf(v.x * wf + bv);
        T[g * 16 + i * 4 + 1][rc] = f2bf(v.y * wf + bv);
        T[g * 16 + i * 4 + 2][rc] = f2bf(v.z * wf + bv);
        T[g * 16 + i * 4 + 3][rc] = f2bf(v.w * wf + bv);
    }
    __syncthreads();
    int n = t >> 2, ch = (t & 3) * 16;
    uint4 o0 = *(const uint4*)&T[n][ch];
    uint4 o1 = *(const uint4*)&T[n][ch + 8];
    u16* dst = xnT + ((size_t)bb * NSP + n0 + n) * CH + c0 + ch;
    *(uint4*)dst = o0;
    *(uint4*)(dst + 8) = o1;
}

// ------- MFMA GEMM for QKV: Y[m][n] = sum_c Aw[m][c] * xnT[n][c] + bias[m] -------
// 64x64 block tile, 4 waves (2x2), each wave 32x32. Frags direct from global (L2).
// Epilogue: m-tiles 0-3 -> qT[b][h][n][c], 4-7 -> kT, 8-11 -> v[b][c][n].
__global__ __launch_bounds__(256) void gemm_qkv(const u16* __restrict__ Aw,
                                                const float* __restrict__ bias,
                                                const u16* __restrict__ xnT,
                                                u16* __restrict__ qT,
                                                u16* __restrict__ kT,
                                                u16* __restrict__ v) {
    const int n0 = blockIdx.x * 64, m0 = blockIdx.y * 64, bb = blockIdx.z;
    const int wave = threadIdx.x >> 6, lane = threadIdx.x & 63;
    const int lq = lane & 15, quad = lane >> 4;
    const int wm = (wave >> 1) * 32, wn = (wave & 1) * 32;
    f32x4 acc[2][2] = {};
    const u16* ap = Aw + (size_t)(m0 + wm + lq) * CH + quad * 8;
    const u16* bp = xnT + ((size_t)bb * NSP + n0 + wn + lq) * CH + quad * 8;
#pragma unroll
    for (int k0 = 0; k0 < CH; k0 += 32) {
        bf16x8 a0 = *(const bf16x8*)(ap + k0);
        bf16x8 a1 = *(const bf16x8*)(ap + 16 * CH + k0);
        bf16x8 b0 = *(const bf16x8*)(bp + k0);
        bf16x8 b1 = *(const bf16x8*)(bp + 16 * CH + k0);
        acc[0][0] = MFMA(a0, b0, acc[0][0], 0, 0, 0);
        acc[0][1] = MFMA(a0, b1, acc[0][1], 0, 0, 0);
        acc[1][0] = MFMA(a1, b0, acc[1][0], 0, 0, 0);
        acc[1][1] = MFMA(a1, b1, acc[1][1], 0, 0, 0);
    }
    const int sect = m0 >> 8;              // 0=Q, 1=K, 2=V
    const int h = (m0 & 255) >> 6;         // head for Q/K sections
#pragma unroll
    for (int im = 0; im < 2; ++im) {
        int ml = wm + im * 16 + quad * 4;  // +r, local m in [0,64)
        float4 bs = *(const float4*)(bias + m0 + ml);
#pragma unroll
        for (int in = 0; in < 2; ++in) {
            int n = n0 + wn + in * 16 + lq;
            f32x4 a = acc[im][in];
            float v0 = a[0] + bs.x, v1 = a[1] + bs.y;
            float v2 = a[2] + bs.z, v3 = a[3] + bs.w;
            if (sect < 2) {
                u16* base = (sect ? kT : qT) +
                            (((size_t)bb * NHD + h) * NSP + n) * HDIM + ml;
                ushort4 o;
                o.x = f2bf(v0); o.y = f2bf(v1); o.z = f2bf(v2); o.w = f2bf(v3);
                *(ushort4*)base = o;
            } else {
                u16* vb = v + ((size_t)bb * CH + (m0 - 512) + ml) * NSP + n;
                vb[0]        = f2bf(v0);
                vb[NSP]      = f2bf(v1);
                vb[2 * NSP]  = f2bf(v2);
                vb[3 * NSP]  = f2bf(v3);
            }
        }
    }
}

// ---------------- MFMA flash attention, barrier-free ----------------
// One block = 4 independent waves, each owning 16 queries. All fragments loaded
// directly from global (qT/kT transposed [n][c], V natural [c][n]); only the
// P C-layout -> A/B-layout transform round-trips through per-wave LDS.
__global__ __launch_bounds__(256) void attn2(const u16* __restrict__ qT,
                                             const u16* __restrict__ kT,
                                             const u16* __restrict__ vN,
                                             u16* __restrict__ aoT) {
    __shared__ u16 Ps[4][16][72];
    const int h = blockIdx.y, bb = blockIdx.z;
    const int wave = threadIdx.x >> 6, lane = threadIdx.x & 63;
    const int lq = lane & 15, quad = lane >> 4;
    const int nq = blockIdx.x * 64 + wave * 16 + lq;     // this lane's query
    const u16* qp = qT + (((size_t)bb * NHD + h) * NSP + nq) * HDIM + quad * 8;
    bf16x8 q0 = *(const bf16x8*)qp;
    bf16x8 q1 = *(const bf16x8*)(qp + 32);
    const u16* kbase = kT + (((size_t)bb * NHD + h) * NSP) * (size_t)HDIM;
    const u16* vbase = vN + ((size_t)bb * CH + h * HDIM) * NSP;
    float m_r = -1e30f, l_r = 0.f;
    f32x4 O[4] = {{0.f,0.f,0.f,0.f},{0.f,0.f,0.f,0.f},
                  {0.f,0.f,0.f,0.f},{0.f,0.f,0.f,0.f}};
    for (int kt = 0; kt < 64; ++kt) {
        const int k0 = kt * 64;
        // S^T[key][q]: A-frag = K[key][c-contig] from kT
        const u16* kp = kbase + (size_t)(k0 + lq) * HDIM + quad * 8;
        f32x4 st[4];
#pragma unroll
        for (int mt = 0; mt < 4; ++mt) {
            bf16x8 a0 = *(const bf16x8*)(kp + mt * 16 * HDIM);
            bf16x8 a1 = *(const bf16x8*)(kp + mt * 16 * HDIM + 32);
            f32x4 acc = {0.f, 0.f, 0.f, 0.f};
            acc = MFMA(a0, q0, acc, 0, 0, 0);
            acc = MFMA(a1, q1, acc, 0, 0, 0);
            st[mt] = acc * 0.125f;   // scale = hd^-0.5
        }
        // online softmax: lane's 16 scores all belong to query nq
        float mx = m_r;
#pragma unroll
        for (int mt = 0; mt < 4; ++mt)
#pragma unroll
            for (int r = 0; r < 4; ++r) mx = fmaxf(mx, st[mt][r]);
        mx = fmaxf(mx, __shfl_xor(mx, 16));
        mx = fmaxf(mx, __shfl_xor(mx, 32));
        float alpha = __expf(m_r - mx);
        m_r = mx;
        float sum = 0.f;
#pragma unroll
        for (int mt = 0; mt < 4; ++mt) {
            float p0 = __expf(st[mt][0] - mx);
            float p1 = __expf(st[mt][1] - mx);
            float p2 = __expf(st[mt][2] - mx);
            float p3 = __expf(st[mt][3] - mx);
            sum += p0 + p1 + p2 + p3;
            ushort4 pk;
            pk.x = f2bf(p0); pk.y = f2bf(p1); pk.z = f2bf(p2); pk.w = f2bf(p3);
            *(ushort4*)&Ps[wave][lq][mt * 16 + quad * 4] = pk;
        }
        sum += __shfl_xor(sum, 16);
        sum += __shfl_xor(sum, 32);
        l_r = l_r * alpha + sum;
        // PV: O[c][q] += V[c][key] * P^T[key][q]; A-frag = V natural (key-contig)
        bf16x8 p0 = *(const bf16x8*)&Ps[wave][lq][quad * 8];
        bf16x8 p1 = *(const bf16x8*)&Ps[wave][lq][32 + quad * 8];
        const u16* vp = vbase + (size_t)lq * NSP + k0 + quad * 8;
#pragma unroll
        for (int mtc = 0; mtc < 4; ++mtc) {
            O[mtc] *= alpha;
            bf16x8 v0 = *(const bf16x8*)(vp + (size_t)(mtc * 16) * NSP);
            bf16x8 v1 = *(const bf16x8*)(vp + (size_t)(mtc * 16) * NSP + 32);
            O[mtc] = MFMA(v0, p0, O[mtc], 0, 0, 0);
            O[mtc] = MFMA(v1, p1, O[mtc], 0, 0, 0);
        }
    }
    float linv = 1.f / l_r;
    u16* op = aoT + ((size_t)bb * NSP + nq) * CH + h * HDIM;
#pragma unroll
    for (int mtc = 0; mtc < 4; ++mtc) {
        ushort4 o;
        o.x = f2bf(O[mtc][0] * linv);
        o.y = f2bf(O[mtc][1] * linv);
        o.z = f2bf(O[mtc][2] * linv);
        o.w = f2bf(O[mtc][3] * linv);
        *(ushort4*)(op + mtc * 16 + quad * 4) = o;
    }
}

// ------- MFMA GEMM proj: out[b][m][n] = sum_c Pw[m][c]*aoT[n][c] + bias + x -------
__global__ __launch_bounds__(256) void gemm_proj(const u16* __restrict__ Aw,
                                                 const float* __restrict__ bias,
                                                 const u16* __restrict__ aoT,
                                                 const float* __restrict__ xres,
                                                 float* __restrict__ out) {
    const int n0 = blockIdx.x * 64, m0 = blockIdx.y * 64, bb = blockIdx.z;
    const int wave = threadIdx.x >> 6, lane = threadIdx.x & 63;
    const int lq = lane & 15, quad = lane >> 4;
    const int wm = (wave >> 1) * 32, wn = (wave & 1) * 32;
    f32x4 acc[2][2] = {};
    const u16* ap = Aw + (size_t)(m0 + wm + lq) * CH + quad * 8;
    const u16* bp = aoT + ((size_t)bb * NSP + n0 + wn + lq) * CH + quad * 8;
#pragma unroll
    for (int k0 = 0; k0 < CH; k0 += 32) {
        bf16x8 a0 = *(const bf16x8*)(ap + k0);
        bf16x8 a1 = *(const bf16x8*)(ap + 16 * CH + k0);
        bf16x8 b0 = *(const bf16x8*)(bp + k0);
        bf16x8 b1 = *(const bf16x8*)(bp + 16 * CH + k0);
        acc[0][0] = MFMA(a0, b0, acc[0][0], 0, 0, 0);
        acc[0][1] = MFMA(a0, b1, acc[0][1], 0, 0, 0);
        acc[1][0] = MFMA(a1, b0, acc[1][0], 0, 0, 0);
        acc[1][1] = MFMA(a1, b1, acc[1][1], 0, 0, 0);
    }
#pragma unroll
    for (int im = 0; im < 2; ++im) {
        int ml = wm + im * 16 + quad * 4;
        float4 bs = *(const float4*)(bias + m0 + ml);
        float bsv[4] = {bs.x, bs.y, bs.z, bs.w};
#pragma unroll
        for (int in = 0; in < 2; ++in) {
            int n = n0 + wn + in * 16 + lq;
            f32x4 a = acc[im][in];
#pragma unroll
            for (int r = 0; r < 4; ++r) {
                size_t idx = ((size_t)bb * CH + m0 + ml + r) * NSP + n;
                out[idx] = a[r] + bsv[r] + xres[idx];
            }
        }
    }
}

extern "C" void kernel_launch(void* const* d_in, const int* in_sizes, int n_in,
                              void* d_out, int out_size, void* d_ws, size_t ws_size,
                              hipStream_t stream) {
    const float* x      = (const float*)d_in[0];
    const float* norm_w = (const float*)d_in[1];
    const float* norm_b = (const float*)d_in[2];
    const float* qkv_w  = (const float*)d_in[3];
    const float* qkv_b  = (const float*)d_in[4];
    const float* proj_w = (const float*)d_in[5];
    const float* proj_b = (const float*)d_in[6];
    float* out = (float*)d_out;

    char* w = (char*)d_ws;
    float* stats = (float*)w;                         // 1 KB
    u16* wqb = (u16*)(w + 1024);                      // 384 KB  (768x256 bf16)
    u16* wpb = (u16*)(w + 1024 + 393216);             // 128 KB  (256x256 bf16)
    u16* xnT = (u16*)(w + 532480);                    // 4 MB  [b][n][c]  (aliased by aoT)
    u16* qT  = (u16*)(w + 532480 + 4194304);          // 4 MB  [b][h][n][c]
    u16* kT  = (u16*)(w + 532480 + 2 * 4194304);      // 4 MB  [b][h][n][c]
    u16* v   = (u16*)(w + 532480 + 3 * 4194304);      // 4 MB  [b][c][n]
    u16* aoT = xnT;                                   // xnT dead after gemm_qkv

    wconv<<<dim3(192), 256, 0, stream>>>(qkv_w, wqb, 3 * CH * CH);
    wconv<<<dim3(64), 256, 0, stream>>>(proj_w, wpb, CH * CH);
    gn_stats<<<dim3(NB * NG), 256, 0, stream>>>(x, stats);
    gn_apply_t<<<dim3(NSP / 64, CH / 64, NB), 256, 0, stream>>>(
        x, stats, norm_w, norm_b, xnT);
    gemm_qkv<<<dim3(NSP / 64, (3 * CH) / 64, NB), 256, 0, stream>>>(
        wqb, qkv_b, xnT, qT, kT, v);
    attn2<<<dim3(NSP / 64, NHD, NB), 256, 0, stream>>>(qT, kT, v, aoT);
    gemm_proj<<<dim3(NSP / 64, CH / 64, NB), 256, 0, stream>>>(
        wpb, proj_b, aoT, x, out);
}

// Round 5
// 348.411 us; speedup vs baseline: 1.0823x; 1.0823x over previous
//
#include <hip/hip_runtime.h>
#include <hip/hip_bf16.h>

#define NSP 4096      // D*H*W
#define CH 256
#define NB 2
#define NG 8
#define CPG 32        // channels per group
#define NHD 4         // heads
#define HDIM 64       // head dim

typedef unsigned short u16;
typedef unsigned int u32;
typedef __attribute__((ext_vector_type(8))) short bf16x8;
typedef __attribute__((ext_vector_type(4))) float f32x4;

#define MFMA __builtin_amdgcn_mfma_f32_16x16x32_bf16

__device__ __forceinline__ u16 f2bf(float f) {
    u32 i = __float_as_uint(f);
    u32 r = (i + 0x7FFFu + ((i >> 16) & 1u)) >> 16;   // round-nearest-even
    return (u16)r;
}

// ---------------- fp32 -> bf16 weight conversion (qkv_w ++ proj_w) ----------------
__global__ __launch_bounds__(256) void wconv2(const float* __restrict__ qw,
                                              const float* __restrict__ pw,
                                              u16* __restrict__ wqb,
                                              u16* __restrict__ wpb) {
    int i = (blockIdx.x * 256 + threadIdx.x) * 4;
    const float* src; u16* dst;
    if (i < 3 * CH * CH) { src = qw + i; dst = wqb + i; }
    else { src = pw + (i - 3 * CH * CH); dst = wpb + (i - 3 * CH * CH); }
    float4 v = *(const float4*)src;
    ushort4 o;
    o.x = f2bf(v.x); o.y = f2bf(v.y); o.z = f2bf(v.z); o.w = f2bf(v.w);
    *(ushort4*)dst = o;
}

// ---------------- GroupNorm partial stats: grid (16 bg, 16 chunks) ----------------
__global__ __launch_bounds__(256) void gn_part(const float* __restrict__ x,
                                               float* __restrict__ partial) {
    const int bg = blockIdx.x, chunk = blockIdx.y;
    const float* p = x + (size_t)bg * (CPG * NSP) + chunk * 8192;
    float s = 0.f, ss = 0.f;
    for (int i = threadIdx.x; i < 2048; i += 256) {   // 8192 floats
        float4 u = ((const float4*)p)[i];
        s += u.x + u.y + u.z + u.w;
        ss += u.x * u.x + u.y * u.y + u.z * u.z + u.w * u.w;
    }
    for (int off = 32; off > 0; off >>= 1) {
        s += __shfl_down(s, off);
        ss += __shfl_down(ss, off);
    }
    __shared__ float red[4][2];
    const int wv = threadIdx.x >> 6;
    if ((threadIdx.x & 63) == 0) { red[wv][0] = s; red[wv][1] = ss; }
    __syncthreads();
    if (threadIdx.x == 0) {
        float ts = red[0][0] + red[1][0] + red[2][0] + red[3][0];
        float tq = red[0][1] + red[1][1] + red[2][1] + red[3][1];
        partial[(bg * 16 + chunk) * 2]     = ts;
        partial[(bg * 16 + chunk) * 2 + 1] = tq;
    }
}

// ------- GroupNorm apply + transpose: x[b][c][n] fp32 -> xnT[b][n][c] bf16 -------
__global__ __launch_bounds__(256) void gn_apply_t(const float* __restrict__ x,
                                                  const float* __restrict__ partial,
                                                  const float* __restrict__ w,
                                                  const float* __restrict__ b,
                                                  u16* __restrict__ xnT) {
    __shared__ u16 T[64][72];   // [n][c], pitch 144 B
    const int n0 = blockIdx.x * 64, c0 = blockIdx.y * 64, bb = blockIdx.z;
    const int t = threadIdx.x;
    const int rc = t & 63;          // channel within tile
    const int g  = t >> 6;          // n-chunk group of 16
    const int c  = c0 + rc;
    const int bg = bb * NG + c / CPG;
    float s = 0.f, q = 0.f;
#pragma unroll
    for (int j = 0; j < 16; ++j) {
        s += partial[(bg * 16 + j) * 2];
        q += partial[(bg * 16 + j) * 2 + 1];
    }
    const float cnt = (float)(CPG * NSP);
    float mean = s / cnt;
    float var  = q / cnt - mean * mean;
    float rstd = rsqrtf(var + 1e-5f);
    float wf = w[c] * rstd, bv = b[c] - mean * wf;
    const float* px = x + ((size_t)bb * CH + c) * NSP + n0 + g * 16;
#pragma unroll
    for (int i = 0; i < 4; ++i) {
        float4 v = *(const float4*)(px + i * 4);
        T[g * 16 + i * 4 + 0][rc] = f2bf(v.x * wf + bv);
        T[g * 16 + i * 4 + 1][rc] = f2bf(v.y * wf + bv);
        T[g * 16 + i * 4 + 2][rc] = f2bf(v.z * wf + bv);
        T[g * 16 + i * 4 + 3][rc] = f2bf(v.w * wf + bv);
    }
    __syncthreads();
    int n = t >> 2, ch = (t & 3) * 16;
    uint4 o0 = *(const uint4*)&T[n][ch];
    uint4 o1 = *(const uint4*)&T[n][ch + 8];
    u16* dst = xnT + ((size_t)bb * NSP + n0 + n) * CH + c0 + ch;
    *(uint4*)dst = o0;
    *(uint4*)(dst + 8) = o1;
}

// ------- MFMA GEMM for QKV: Y[m][n] = sum_c Aw[m][c] * xnT[n][c] + bias[m] -------
__global__ __launch_bounds__(256) void gemm_qkv(const u16* __restrict__ Aw,
                                                const float* __restrict__ bias,
                                                const u16* __restrict__ xnT,
                                                u16* __restrict__ qT,
                                                u16* __restrict__ kT,
                                                u16* __restrict__ v) {
    const int n0 = blockIdx.x * 64, m0 = blockIdx.y * 64, bb = blockIdx.z;
    const int wave = threadIdx.x >> 6, lane = threadIdx.x & 63;
    const int lq = lane & 15, quad = lane >> 4;
    const int wm = (wave >> 1) * 32, wn = (wave & 1) * 32;
    f32x4 acc[2][2] = {};
    const u16* ap = Aw + (size_t)(m0 + wm + lq) * CH + quad * 8;
    const u16* bp = xnT + ((size_t)bb * NSP + n0 + wn + lq) * CH + quad * 8;
#pragma unroll
    for (int k0 = 0; k0 < CH; k0 += 32) {
        bf16x8 a0 = *(const bf16x8*)(ap + k0);
        bf16x8 a1 = *(const bf16x8*)(ap + 16 * CH + k0);
        bf16x8 b0 = *(const bf16x8*)(bp + k0);
        bf16x8 b1 = *(const bf16x8*)(bp + 16 * CH + k0);
        acc[0][0] = MFMA(a0, b0, acc[0][0], 0, 0, 0);
        acc[0][1] = MFMA(a0, b1, acc[0][1], 0, 0, 0);
        acc[1][0] = MFMA(a1, b0, acc[1][0], 0, 0, 0);
        acc[1][1] = MFMA(a1, b1, acc[1][1], 0, 0, 0);
    }
    const int sect = m0 >> 8;              // 0=Q, 1=K, 2=V
    const int h = (m0 & 255) >> 6;         // head for Q/K sections
#pragma unroll
    for (int im = 0; im < 2; ++im) {
        int ml = wm + im * 16 + quad * 4;  // +r, local m in [0,64)
        float4 bs = *(const float4*)(bias + m0 + ml);
#pragma unroll
        for (int in = 0; in < 2; ++in) {
            int n = n0 + wn + in * 16 + lq;
            f32x4 a = acc[im][in];
            float v0 = a[0] + bs.x, v1 = a[1] + bs.y;
            float v2 = a[2] + bs.z, v3 = a[3] + bs.w;
            if (sect < 2) {
                u16* base = (sect ? kT : qT) +
                            (((size_t)bb * NHD + h) * NSP + n) * HDIM + ml;
                ushort4 o;
                o.x = f2bf(v0); o.y = f2bf(v1); o.z = f2bf(v2); o.w = f2bf(v3);
                *(ushort4*)base = o;
            } else {
                u16* vb = v + ((size_t)bb * CH + (m0 - 512) + ml) * NSP + n;
                vb[0]        = f2bf(v0);
                vb[NSP]      = f2bf(v1);
                vb[2 * NSP]  = f2bf(v2);
                vb[3 * NSP]  = f2bf(v3);
            }
        }
    }
}

// ---------------- split-K MFMA flash attention ----------------
// One block = 16 queries; 4 waves each process a disjoint 1024-key quarter with
// private online softmax, then merge (m,l,O) once via LDS. All fragments direct
// from global (qT/kT [n][c], V natural [c][n]); P round-trips per-wave LDS.
__global__ __launch_bounds__(256, 8) void attn3(const u16* __restrict__ qT,
                                                const u16* __restrict__ kT,
                                                const u16* __restrict__ vN,
                                                u16* __restrict__ aoT) {
    __shared__ __align__(16) char smem[17920];
    u16 (*Ps)[16][72]  = reinterpret_cast<u16(*)[16][72]>(smem);    // per-wave P
    float (*Ob)[16][68] = reinterpret_cast<float(*)[16][68]>(smem); // merge (aliases Ps)
    float (*Ml)[16][2] = reinterpret_cast<float(*)[16][2]>(smem + 17408);
    const int h = blockIdx.y, bb = blockIdx.z;
    const int wave = threadIdx.x >> 6, lane = threadIdx.x & 63;
    const int lq = lane & 15, quad = lane >> 4;
    const int nq = blockIdx.x * 16 + lq;                 // this lane's query
    const u16* qp = qT + (((size_t)bb * NHD + h) * NSP + nq) * HDIM + quad * 8;
    bf16x8 q0 = *(const bf16x8*)qp;
    bf16x8 q1 = *(const bf16x8*)(qp + 32);
    const u16* kbase = kT + (((size_t)bb * NHD + h) * NSP) * (size_t)HDIM;
    const u16* vbase = vN + ((size_t)bb * CH + h * HDIM) * NSP;
    float m_r = -1e30f, l_r = 0.f;
    f32x4 O[4] = {{0.f,0.f,0.f,0.f},{0.f,0.f,0.f,0.f},
                  {0.f,0.f,0.f,0.f},{0.f,0.f,0.f,0.f}};
    for (int kt = 0; kt < 16; ++kt) {
        const int k0 = (wave * 16 + kt) * 64;            // this wave's key quarter
        const u16* kp = kbase + (size_t)(k0 + lq) * HDIM + quad * 8;
        f32x4 st[4];
#pragma unroll
        for (int mt = 0; mt < 4; ++mt) {
            bf16x8 a0 = *(const bf16x8*)(kp + mt * 16 * HDIM);
            bf16x8 a1 = *(const bf16x8*)(kp + mt * 16 * HDIM + 32);
            f32x4 acc = {0.f, 0.f, 0.f, 0.f};
            acc = MFMA(a0, q0, acc, 0, 0, 0);
            acc = MFMA(a1, q1, acc, 0, 0, 0);
            st[mt] = acc * 0.125f;   // scale = hd^-0.5
        }
        float mx = m_r;
#pragma unroll
        for (int mt = 0; mt < 4; ++mt)
#pragma unroll
            for (int r = 0; r < 4; ++r) mx = fmaxf(mx, st[mt][r]);
        mx = fmaxf(mx, __shfl_xor(mx, 16));
        mx = fmaxf(mx, __shfl_xor(mx, 32));
        float alpha = __expf(m_r - mx);
        m_r = mx;
        float sum = 0.f;
#pragma unroll
        for (int mt = 0; mt < 4; ++mt) {
            float p0 = __expf(st[mt][0] - mx);
            float p1 = __expf(st[mt][1] - mx);
            float p2 = __expf(st[mt][2] - mx);
            float p3 = __expf(st[mt][3] - mx);
            sum += p0 + p1 + p2 + p3;
            ushort4 pk;
            pk.x = f2bf(p0); pk.y = f2bf(p1); pk.z = f2bf(p2); pk.w = f2bf(p3);
            *(ushort4*)&Ps[wave][lq][mt * 16 + quad * 4] = pk;
        }
        sum += __shfl_xor(sum, 16);
        sum += __shfl_xor(sum, 32);
        l_r = l_r * alpha + sum;
        bf16x8 p0 = *(const bf16x8*)&Ps[wave][lq][quad * 8];
        bf16x8 p1 = *(const bf16x8*)&Ps[wave][lq][32 + quad * 8];
        const u16* vp = vbase + (size_t)lq * NSP + k0 + quad * 8;
#pragma unroll
        for (int mtc = 0; mtc < 4; ++mtc) {
            O[mtc] *= alpha;
            bf16x8 v0 = *(const bf16x8*)(vp + (size_t)(mtc * 16) * NSP);
            bf16x8 v1 = *(const bf16x8*)(vp + (size_t)(mtc * 16) * NSP + 32);
            O[mtc] = MFMA(v0, p0, O[mtc], 0, 0, 0);
            O[mtc] = MFMA(v1, p1, O[mtc], 0, 0, 0);
        }
    }
    // ---- cross-wave merge ----
    if (lane < 16) { Ml[wave][lane][0] = m_r; Ml[wave][lane][1] = l_r; }
    __syncthreads();                       // also: all Ps reads done before Ob writes
    float gm = fmaxf(fmaxf(Ml[0][lq][0], Ml[1][lq][0]),
                     fmaxf(Ml[2][lq][0], Ml[3][lq][0]));
    float gl = Ml[0][lq][1] * __expf(Ml[0][lq][0] - gm)
             + Ml[1][lq][1] * __expf(Ml[1][lq][0] - gm)
             + Ml[2][lq][1] * __expf(Ml[2][lq][0] - gm)
             + Ml[3][lq][1] * __expf(Ml[3][lq][0] - gm);
    float aw = __expf(m_r - gm);
#pragma unroll
    for (int mtc = 0; mtc < 4; ++mtc)
        *(f32x4*)&Ob[wave][lq][mtc * 16 + quad * 4] = O[mtc] * aw;
    __syncthreads();
    // wave sums its own 16-channel slice across the 4 partials
    const int cbase = wave * 16 + quad * 4;
    f32x4 sacc = *(const f32x4*)&Ob[0][lq][cbase];
    sacc += *(const f32x4*)&Ob[1][lq][cbase];
    sacc += *(const f32x4*)&Ob[2][lq][cbase];
    sacc += *(const f32x4*)&Ob[3][lq][cbase];
    float linv = 1.f / gl;
    ushort4 o;
    o.x = f2bf(sacc[0] * linv);
    o.y = f2bf(sacc[1] * linv);
    o.z = f2bf(sacc[2] * linv);
    o.w = f2bf(sacc[3] * linv);
    *(ushort4*)(aoT + ((size_t)bb * NSP + nq) * CH + h * HDIM + cbase) = o;
}

// ------- MFMA GEMM proj: out[b][m][n] = sum_c Pw[m][c]*aoT[n][c] + bias + x -------
__global__ __launch_bounds__(256) void gemm_proj(const u16* __restrict__ Aw,
                                                 const float* __restrict__ bias,
                                                 const u16* __restrict__ aoT,
                                                 const float* __restrict__ xres,
                                                 float* __restrict__ out) {
    const int n0 = blockIdx.x * 64, m0 = blockIdx.y * 64, bb = blockIdx.z;
    const int wave = threadIdx.x >> 6, lane = threadIdx.x & 63;
    const int lq = lane & 15, quad = lane >> 4;
    const int wm = (wave >> 1) * 32, wn = (wave & 1) * 32;
    f32x4 acc[2][2] = {};
    const u16* ap = Aw + (size_t)(m0 + wm + lq) * CH + quad * 8;
    const u16* bp = aoT + ((size_t)bb * NSP + n0 + wn + lq) * CH + quad * 8;
#pragma unroll
    for (int k0 = 0; k0 < CH; k0 += 32) {
        bf16x8 a0 = *(const bf16x8*)(ap + k0);
        bf16x8 a1 = *(const bf16x8*)(ap + 16 * CH + k0);
        bf16x8 b0 = *(const bf16x8*)(bp + k0);
        bf16x8 b1 = *(const bf16x8*)(bp + 16 * CH + k0);
        acc[0][0] = MFMA(a0, b0, acc[0][0], 0, 0, 0);
        acc[0][1] = MFMA(a0, b1, acc[0][1], 0, 0, 0);
        acc[1][0] = MFMA(a1, b0, acc[1][0], 0, 0, 0);
        acc[1][1] = MFMA(a1, b1, acc[1][1], 0, 0, 0);
    }
#pragma unroll
    for (int im = 0; im < 2; ++im) {
        int ml = wm + im * 16 + quad * 4;
        float4 bs = *(const float4*)(bias + m0 + ml);
        float bsv[4] = {bs.x, bs.y, bs.z, bs.w};
#pragma unroll
        for (int in = 0; in < 2; ++in) {
            int n = n0 + wn + in * 16 + lq;
            f32x4 a = acc[im][in];
#pragma unroll
            for (int r = 0; r < 4; ++r) {
                size_t idx = ((size_t)bb * CH + m0 + ml + r) * NSP + n;
                out[idx] = a[r] + bsv[r] + xres[idx];
            }
        }
    }
}

extern "C" void kernel_launch(void* const* d_in, const int* in_sizes, int n_in,
                              void* d_out, int out_size, void* d_ws, size_t ws_size,
                              hipStream_t stream) {
    const float* x      = (const float*)d_in[0];
    const float* norm_w = (const float*)d_in[1];
    const float* norm_b = (const float*)d_in[2];
    const float* qkv_w  = (const float*)d_in[3];
    const float* qkv_b  = (const float*)d_in[4];
    const float* proj_w = (const float*)d_in[5];
    const float* proj_b = (const float*)d_in[6];
    float* out = (float*)d_out;

    char* w = (char*)d_ws;
    float* partial = (float*)w;                       // 4 KB (16x16x2 fp32)
    u16* wqb = (u16*)(w + 4096);                      // 384 KB (768x256 bf16)
    u16* wpb = (u16*)(w + 4096 + 393216);             // 128 KB (256x256 bf16)
    u16* xnT = (u16*)(w + 528384);                    // 4 MB [b][n][c] (aliased by aoT)
    u16* qT  = (u16*)(w + 528384 + 4194304);          // 4 MB [b][h][n][c]
    u16* kT  = (u16*)(w + 528384 + 2 * 4194304);      // 4 MB [b][h][n][c]
    u16* v   = (u16*)(w + 528384 + 3 * 4194304);      // 4 MB [b][c][n]
    u16* aoT = xnT;                                   // xnT dead after gemm_qkv

    wconv2<<<dim3(256), 256, 0, stream>>>(qkv_w, proj_w, wqb, wpb);
    gn_part<<<dim3(NB * NG, 16), 256, 0, stream>>>(x, partial);
    gn_apply_t<<<dim3(NSP / 64, CH / 64, NB), 256, 0, stream>>>(
        x, partial, norm_w, norm_b, xnT);
    gemm_qkv<<<dim3(NSP / 64, (3 * CH) / 64, NB), 256, 0, stream>>>(
        wqb, qkv_b, xnT, qT, kT, v);
    attn3<<<dim3(NSP / 16, NHD, NB), 256, 0, stream>>>(qT, kT, v, aoT);
    gemm_proj<<<dim3(NSP / 64, CH / 64, NB), 256, 0, stream>>>(
        wpb, proj_b, aoT, x, out);
}

// Round 6
// 204.640 us; speedup vs baseline: 1.8426x; 1.7026x over previous
//
#include <hip/hip_runtime.h>
#include <hip/hip_bf16.h>

#define NSP 4096      // D*H*W
#define CH 256
#define NB 2
#define NG 8
#define CPG 32        // channels per group
#define NHD 4         // heads
#define HDIM 64       // head dim

typedef unsigned short u16;
typedef unsigned int u32;
typedef __attribute__((ext_vector_type(8))) short bf16x8;
typedef __attribute__((ext_vector_type(4))) float f32x4;

#define MFMA __builtin_amdgcn_mfma_f32_16x16x32_bf16

__device__ __forceinline__ u16 f2bf(float f) {
    u32 i = __float_as_uint(f);
    u32 r = (i + 0x7FFFu + ((i >> 16) & 1u)) >> 16;   // round-nearest-even
    return (u16)r;
}

// ---------------- fp32 -> bf16 weight conversion (qkv_w ++ proj_w) ----------------
__global__ __launch_bounds__(256) void wconv2(const float* __restrict__ qw,
                                              const float* __restrict__ pw,
                                              u16* __restrict__ wqb,
                                              u16* __restrict__ wpb) {
    int i = (blockIdx.x * 256 + threadIdx.x) * 4;
    const float* src; u16* dst;
    if (i < 3 * CH * CH) { src = qw + i; dst = wqb + i; }
    else { src = pw + (i - 3 * CH * CH); dst = wpb + (i - 3 * CH * CH); }
    float4 v = *(const float4*)src;
    ushort4 o;
    o.x = f2bf(v.x); o.y = f2bf(v.y); o.z = f2bf(v.z); o.w = f2bf(v.w);
    *(ushort4*)dst = o;
}

// ---------------- GroupNorm partial stats: grid (16 bg, 16 chunks) ----------------
__global__ __launch_bounds__(256) void gn_part(const float* __restrict__ x,
                                               float* __restrict__ partial) {
    const int bg = blockIdx.x, chunk = blockIdx.y;
    const float* p = x + (size_t)bg * (CPG * NSP) + chunk * 8192;
    float s = 0.f, ss = 0.f;
    for (int i = threadIdx.x; i < 2048; i += 256) {   // 8192 floats
        float4 u = ((const float4*)p)[i];
        s += u.x + u.y + u.z + u.w;
        ss += u.x * u.x + u.y * u.y + u.z * u.z + u.w * u.w;
    }
    for (int off = 32; off > 0; off >>= 1) {
        s += __shfl_down(s, off);
        ss += __shfl_down(ss, off);
    }
    __shared__ float red[4][2];
    const int wv = threadIdx.x >> 6;
    if ((threadIdx.x & 63) == 0) { red[wv][0] = s; red[wv][1] = ss; }
    __syncthreads();
    if (threadIdx.x == 0) {
        float ts = red[0][0] + red[1][0] + red[2][0] + red[3][0];
        float tq = red[0][1] + red[1][1] + red[2][1] + red[3][1];
        partial[(bg * 16 + chunk) * 2]     = ts;
        partial[(bg * 16 + chunk) * 2 + 1] = tq;
    }
}

// ------- GroupNorm apply + transpose: x[b][c][n] fp32 -> xnT[b][n][c] bf16 -------
__global__ __launch_bounds__(256) void gn_apply_t(const float* __restrict__ x,
                                                  const float* __restrict__ partial,
                                                  const float* __restrict__ w,
                                                  const float* __restrict__ b,
                                                  u16* __restrict__ xnT) {
    __shared__ u16 T[64][72];   // [n][c], pitch 144 B
    const int n0 = blockIdx.x * 64, c0 = blockIdx.y * 64, bb = blockIdx.z;
    const int t = threadIdx.x;
    const int rc = t & 63;          // channel within tile
    const int g  = t >> 6;          // n-chunk group of 16
    const int c  = c0 + rc;
    const int bg = bb * NG + c / CPG;
    float s = 0.f, q = 0.f;
#pragma unroll
    for (int j = 0; j < 16; ++j) {
        s += partial[(bg * 16 + j) * 2];
        q += partial[(bg * 16 + j) * 2 + 1];
    }
    const float cnt = (float)(CPG * NSP);
    float mean = s / cnt;
    float var  = q / cnt - mean * mean;
    float rstd = rsqrtf(var + 1e-5f);
    float wf = w[c] * rstd, bv = b[c] - mean * wf;
    const float* px = x + ((size_t)bb * CH + c) * NSP + n0 + g * 16;
#pragma unroll
    for (int i = 0; i < 4; ++i) {
        float4 v = *(const float4*)(px + i * 4);
        T[g * 16 + i * 4 + 0][rc] = f2bf(v.x * wf + bv);
        T[g * 16 + i * 4 + 1][rc] = f2bf(v.y * wf + bv);
        T[g * 16 + i * 4 + 2][rc] = f2bf(v.z * wf + bv);
        T[g * 16 + i * 4 + 3][rc] = f2bf(v.w * wf + bv);
    }
    __syncthreads();
    int n = t >> 2, ch = (t & 3) * 16;
    uint4 o0 = *(const uint4*)&T[n][ch];
    uint4 o1 = *(const uint4*)&T[n][ch + 8];
    u16* dst = xnT + ((size_t)bb * NSP + n0 + n) * CH + c0 + ch;
    *(uint4*)dst = o0;
    *(uint4*)(dst + 8) = o1;
}

// ------- MFMA GEMM for QKV: Y[m][n] = sum_c Aw[m][c] * xnT[n][c] + bias[m] -------
__global__ __launch_bounds__(256) void gemm_qkv(const u16* __restrict__ Aw,
                                                const float* __restrict__ bias,
                                                const u16* __restrict__ xnT,
                                                u16* __restrict__ qT,
                                                u16* __restrict__ kT,
                                                u16* __restrict__ v) {
    const int n0 = blockIdx.x * 64, m0 = blockIdx.y * 64, bb = blockIdx.z;
    const int wave = threadIdx.x >> 6, lane = threadIdx.x & 63;
    const int lq = lane & 15, quad = lane >> 4;
    const int wm = (wave >> 1) * 32, wn = (wave & 1) * 32;
    f32x4 acc[2][2] = {};
    const u16* ap = Aw + (size_t)(m0 + wm + lq) * CH + quad * 8;
    const u16* bp = xnT + ((size_t)bb * NSP + n0 + wn + lq) * CH + quad * 8;
#pragma unroll
    for (int k0 = 0; k0 < CH; k0 += 32) {
        bf16x8 a0 = *(const bf16x8*)(ap + k0);
        bf16x8 a1 = *(const bf16x8*)(ap + 16 * CH + k0);
        bf16x8 b0 = *(const bf16x8*)(bp + k0);
        bf16x8 b1 = *(const bf16x8*)(bp + 16 * CH + k0);
        acc[0][0] = MFMA(a0, b0, acc[0][0], 0, 0, 0);
        acc[0][1] = MFMA(a0, b1, acc[0][1], 0, 0, 0);
        acc[1][0] = MFMA(a1, b0, acc[1][0], 0, 0, 0);
        acc[1][1] = MFMA(a1, b1, acc[1][1], 0, 0, 0);
    }
    const int sect = m0 >> 8;              // 0=Q, 1=K, 2=V
    const int h = (m0 & 255) >> 6;         // head for Q/K sections
#pragma unroll
    for (int im = 0; im < 2; ++im) {
        int ml = wm + im * 16 + quad * 4;  // +r, local m in [0,64)
        float4 bs = *(const float4*)(bias + m0 + ml);
#pragma unroll
        for (int in = 0; in < 2; ++in) {
            int n = n0 + wn + in * 16 + lq;
            f32x4 a = acc[im][in];
            float v0 = a[0] + bs.x, v1 = a[1] + bs.y;
            float v2 = a[2] + bs.z, v3 = a[3] + bs.w;
            if (sect < 2) {
                u16* base = (sect ? kT : qT) +
                            (((size_t)bb * NHD + h) * NSP + n) * HDIM + ml;
                ushort4 o;
                o.x = f2bf(v0); o.y = f2bf(v1); o.z = f2bf(v2); o.w = f2bf(v3);
                *(ushort4*)base = o;
            } else {
                u16* vb = v + ((size_t)bb * CH + (m0 - 512) + ml) * NSP + n;
                vb[0]        = f2bf(v0);
                vb[NSP]      = f2bf(v1);
                vb[2 * NSP]  = f2bf(v2);
                vb[3 * NSP]  = f2bf(v3);
            }
        }
    }
}

// ---------------- LDS-shared MFMA flash attention ----------------
// One block = 128 queries, 8 waves x 16 q, full 4096-key sweep with online
// softmax (verified attn3 inner math). K/V tiles staged once per block into
// LDS (vectorized copy: kT is pre-transposed [n][c], V natural [c][n]) and
// shared by all 8 waves -> 8x less L2 traffic than round-5. Register-prefetch
// of tile kt+1 overlaps global latency with tile-kt compute.
__global__ __launch_bounds__(512) void attn4(const u16* __restrict__ qT,
                                             const u16* __restrict__ kT,
                                             const u16* __restrict__ vN,
                                             u16* __restrict__ aoT) {
    __shared__ u16 Ks[64][72];      // [key][ch]
    __shared__ u16 Vs[64][72];      // [ch][key]
    __shared__ u16 Ps[8][16][72];   // per-wave P round-trip
    const int h = blockIdx.y, bb = blockIdx.z;
    const int t = threadIdx.x;
    const int wave = t >> 6, lane = t & 63;
    const int lq = lane & 15, quad = lane >> 4;
    const int nq = blockIdx.x * 128 + wave * 16 + lq;    // this lane's query
    const u16* qp = qT + (((size_t)bb * NHD + h) * NSP + nq) * HDIM + quad * 8;
    bf16x8 q0 = *(const bf16x8*)qp;
    bf16x8 q1 = *(const bf16x8*)(qp + 32);
    const u16* kbase = kT + (((size_t)bb * NHD + h) * NSP) * (size_t)HDIM;
    const u16* vbase = vN + ((size_t)bb * CH + h * HDIM) * NSP;
    // staging: 512 threads x 16 B = 16 KB (K row=key, V row=ch; both 8 KB)
    const int srow = t >> 3, scol = (t & 7) * 8;
    uint4 kreg = *(const uint4*)(kbase + (size_t)srow * HDIM + scol);
    uint4 vreg = *(const uint4*)(vbase + (size_t)srow * NSP + scol);

    float m_r = -1e30f, l_r = 0.f;
    f32x4 O[4] = {{0.f,0.f,0.f,0.f},{0.f,0.f,0.f,0.f},
                  {0.f,0.f,0.f,0.f},{0.f,0.f,0.f,0.f}};
    for (int kt = 0; kt < 64; ++kt) {
        __syncthreads();                 // prev iter's LDS reads complete
        *(uint4*)&Ks[srow][scol] = kreg;
        *(uint4*)&Vs[srow][scol] = vreg;
        __syncthreads();
        if (kt < 63) {                   // prefetch next tile during compute
            const int k1 = (kt + 1) * 64;
            kreg = *(const uint4*)(kbase + (size_t)(k1 + srow) * HDIM + scol);
            vreg = *(const uint4*)(vbase + (size_t)srow * NSP + k1 + scol);
        }
        // S^T[key][q]: A-frag = Ks[key][ch-contig], B-frag = Q
        f32x4 st[4];
#pragma unroll
        for (int mt = 0; mt < 4; ++mt) {
            bf16x8 a0 = *(const bf16x8*)&Ks[mt * 16 + lq][quad * 8];
            bf16x8 a1 = *(const bf16x8*)&Ks[mt * 16 + lq][32 + quad * 8];
            f32x4 acc = {0.f, 0.f, 0.f, 0.f};
            acc = MFMA(a0, q0, acc, 0, 0, 0);
            acc = MFMA(a1, q1, acc, 0, 0, 0);
            st[mt] = acc * 0.125f;       // scale = hd^-0.5
        }
        // online softmax: lane's 16 scores all belong to query nq
        float mx = m_r;
#pragma unroll
        for (int mt = 0; mt < 4; ++mt)
#pragma unroll
            for (int r = 0; r < 4; ++r) mx = fmaxf(mx, st[mt][r]);
        mx = fmaxf(mx, __shfl_xor(mx, 16));
        mx = fmaxf(mx, __shfl_xor(mx, 32));
        float alpha = __expf(m_r - mx);
        m_r = mx;
        float sum = 0.f;
#pragma unroll
        for (int mt = 0; mt < 4; ++mt) {
            float p0 = __expf(st[mt][0] - mx);
            float p1 = __expf(st[mt][1] - mx);
            float p2 = __expf(st[mt][2] - mx);
            float p3 = __expf(st[mt][3] - mx);
            sum += p0 + p1 + p2 + p3;
            ushort4 pk;
            pk.x = f2bf(p0); pk.y = f2bf(p1); pk.z = f2bf(p2); pk.w = f2bf(p3);
            *(ushort4*)&Ps[wave][lq][mt * 16 + quad * 4] = pk;
        }
        sum += __shfl_xor(sum, 16);
        sum += __shfl_xor(sum, 32);
        l_r = l_r * alpha + sum;
        // PV: O[c][q] += V[c][key] * P^T[key][q]
        bf16x8 p0 = *(const bf16x8*)&Ps[wave][lq][quad * 8];
        bf16x8 p1 = *(const bf16x8*)&Ps[wave][lq][32 + quad * 8];
#pragma unroll
        for (int mtc = 0; mtc < 4; ++mtc) {
            O[mtc] *= alpha;
            bf16x8 v0 = *(const bf16x8*)&Vs[mtc * 16 + lq][quad * 8];
            bf16x8 v1 = *(const bf16x8*)&Vs[mtc * 16 + lq][32 + quad * 8];
            O[mtc] = MFMA(v0, p0, O[mtc], 0, 0, 0);
            O[mtc] = MFMA(v1, p1, O[mtc], 0, 0, 0);
        }
    }
    float linv = 1.f / l_r;
    u16* op = aoT + ((size_t)bb * NSP + nq) * CH + h * HDIM;
#pragma unroll
    for (int mtc = 0; mtc < 4; ++mtc) {
        ushort4 o;
        o.x = f2bf(O[mtc][0] * linv);
        o.y = f2bf(O[mtc][1] * linv);
        o.z = f2bf(O[mtc][2] * linv);
        o.w = f2bf(O[mtc][3] * linv);
        *(ushort4*)(op + mtc * 16 + quad * 4) = o;
    }
}

// ------- MFMA GEMM proj: out[b][m][n] = sum_c Pw[m][c]*aoT[n][c] + bias + x -------
__global__ __launch_bounds__(256) void gemm_proj(const u16* __restrict__ Aw,
                                                 const float* __restrict__ bias,
                                                 const u16* __restrict__ aoT,
                                                 const float* __restrict__ xres,
                                                 float* __restrict__ out) {
    const int n0 = blockIdx.x * 64, m0 = blockIdx.y * 64, bb = blockIdx.z;
    const int wave = threadIdx.x >> 6, lane = threadIdx.x & 63;
    const int lq = lane & 15, quad = lane >> 4;
    const int wm = (wave >> 1) * 32, wn = (wave & 1) * 32;
    f32x4 acc[2][2] = {};
    const u16* ap = Aw + (size_t)(m0 + wm + lq) * CH + quad * 8;
    const u16* bp = aoT + ((size_t)bb * NSP + n0 + wn + lq) * CH + quad * 8;
#pragma unroll
    for (int k0 = 0; k0 < CH; k0 += 32) {
        bf16x8 a0 = *(const bf16x8*)(ap + k0);
        bf16x8 a1 = *(const bf16x8*)(ap + 16 * CH + k0);
        bf16x8 b0 = *(const bf16x8*)(bp + k0);
        bf16x8 b1 = *(const bf16x8*)(bp + 16 * CH + k0);
        acc[0][0] = MFMA(a0, b0, acc[0][0], 0, 0, 0);
        acc[0][1] = MFMA(a0, b1, acc[0][1], 0, 0, 0);
        acc[1][0] = MFMA(a1, b0, acc[1][0], 0, 0, 0);
        acc[1][1] = MFMA(a1, b1, acc[1][1], 0, 0, 0);
    }
#pragma unroll
    for (int im = 0; im < 2; ++im) {
        int ml = wm + im * 16 + quad * 4;
        float4 bs = *(const float4*)(bias + m0 + ml);
        float bsv[4] = {bs.x, bs.y, bs.z, bs.w};
#pragma unroll
        for (int in = 0; in < 2; ++in) {
            int n = n0 + wn + in * 16 + lq;
            f32x4 a = acc[im][in];
#pragma unroll
            for (int r = 0; r < 4; ++r) {
                size_t idx = ((size_t)bb * CH + m0 + ml + r) * NSP + n;
                out[idx] = a[r] + bsv[r] + xres[idx];
            }
        }
    }
}

extern "C" void kernel_launch(void* const* d_in, const int* in_sizes, int n_in,
                              void* d_out, int out_size, void* d_ws, size_t ws_size,
                              hipStream_t stream) {
    const float* x      = (const float*)d_in[0];
    const float* norm_w = (const float*)d_in[1];
    const float* norm_b = (const float*)d_in[2];
    const float* qkv_w  = (const float*)d_in[3];
    const float* qkv_b  = (const float*)d_in[4];
    const float* proj_w = (const float*)d_in[5];
    const float* proj_b = (const float*)d_in[6];
    float* out = (float*)d_out;

    char* w = (char*)d_ws;
    float* partial = (float*)w;                       // 4 KB (16x16x2 fp32)
    u16* wqb = (u16*)(w + 4096);                      // 384 KB (768x256 bf16)
    u16* wpb = (u16*)(w + 4096 + 393216);             // 128 KB (256x256 bf16)
    u16* xnT = (u16*)(w + 528384);                    // 4 MB [b][n][c] (aliased by aoT)
    u16* qT  = (u16*)(w + 528384 + 4194304);          // 4 MB [b][h][n][c]
    u16* kT  = (u16*)(w + 528384 + 2 * 4194304);      // 4 MB [b][h][n][c]
    u16* v   = (u16*)(w + 528384 + 3 * 4194304);      // 4 MB [b][c][n]
    u16* aoT = xnT;                                   // xnT dead after gemm_qkv

    wconv2<<<dim3(256), 256, 0, stream>>>(qkv_w, proj_w, wqb, wpb);
    gn_part<<<dim3(NB * NG, 16), 256, 0, stream>>>(x, partial);
    gn_apply_t<<<dim3(NSP / 64, CH / 64, NB), 256, 0, stream>>>(
        x, partial, norm_w, norm_b, xnT);
    gemm_qkv<<<dim3(NSP / 64, (3 * CH) / 64, NB), 256, 0, stream>>>(
        wqb, qkv_b, xnT, qT, kT, v);
    attn4<<<dim3(NSP / 128, NHD, NB), 512, 0, stream>>>(qT, kT, v, aoT);
    gemm_proj<<<dim3(NSP / 64, CH / 64, NB), 256, 0, stream>>>(
        wpb, proj_b, aoT, x, out);
}

// Round 7
// 202.192 us; speedup vs baseline: 1.8649x; 1.0121x over previous
//
#include <hip/hip_runtime.h>
#include <hip/hip_bf16.h>

#define NSP 4096      // D*H*W
#define CH 256
#define NB 2
#define NG 8
#define CPG 32        // channels per group
#define NHD 4         // heads
#define HDIM 64       // head dim

typedef unsigned short u16;
typedef unsigned int u32;
typedef __attribute__((ext_vector_type(8))) short bf16x8;
typedef __attribute__((ext_vector_type(4))) float f32x4;

#define MFMA __builtin_amdgcn_mfma_f32_16x16x32_bf16

__device__ __forceinline__ u16 f2bf(float f) {
    u32 i = __float_as_uint(f);
    u32 r = (i + 0x7FFFu + ((i >> 16) & 1u)) >> 16;   // round-nearest-even
    return (u16)r;
}

// ---------------- fp32 -> bf16 weight conversion (qkv_w ++ proj_w) ----------------
__global__ __launch_bounds__(256) void wconv2(const float* __restrict__ qw,
                                              const float* __restrict__ pw,
                                              u16* __restrict__ wqb,
                                              u16* __restrict__ wpb) {
    int i = (blockIdx.x * 256 + threadIdx.x) * 4;
    const float* src; u16* dst;
    if (i < 3 * CH * CH) { src = qw + i; dst = wqb + i; }
    else { src = pw + (i - 3 * CH * CH); dst = wpb + (i - 3 * CH * CH); }
    float4 v = *(const float4*)src;
    ushort4 o;
    o.x = f2bf(v.x); o.y = f2bf(v.y); o.z = f2bf(v.z); o.w = f2bf(v.w);
    *(ushort4*)dst = o;
}

// ---------------- GroupNorm partial stats: grid (16 bg, 16 chunks) ----------------
__global__ __launch_bounds__(256) void gn_part(const float* __restrict__ x,
                                               float* __restrict__ partial) {
    const int bg = blockIdx.x, chunk = blockIdx.y;
    const float* p = x + (size_t)bg * (CPG * NSP) + chunk * 8192;
    float s = 0.f, ss = 0.f;
    for (int i = threadIdx.x; i < 2048; i += 256) {   // 8192 floats
        float4 u = ((const float4*)p)[i];
        s += u.x + u.y + u.z + u.w;
        ss += u.x * u.x + u.y * u.y + u.z * u.z + u.w * u.w;
    }
    for (int off = 32; off > 0; off >>= 1) {
        s += __shfl_down(s, off);
        ss += __shfl_down(ss, off);
    }
    __shared__ float red[4][2];
    const int wv = threadIdx.x >> 6;
    if ((threadIdx.x & 63) == 0) { red[wv][0] = s; red[wv][1] = ss; }
    __syncthreads();
    if (threadIdx.x == 0) {
        float ts = red[0][0] + red[1][0] + red[2][0] + red[3][0];
        float tq = red[0][1] + red[1][1] + red[2][1] + red[3][1];
        partial[(bg * 16 + chunk) * 2]     = ts;
        partial[(bg * 16 + chunk) * 2 + 1] = tq;
    }
}

// ------- GroupNorm apply + transpose: x[b][c][n] fp32 -> xnT[b][n][c] bf16 -------
__global__ __launch_bounds__(256) void gn_apply_t(const float* __restrict__ x,
                                                  const float* __restrict__ partial,
                                                  const float* __restrict__ w,
                                                  const float* __restrict__ b,
                                                  u16* __restrict__ xnT) {
    __shared__ u16 T[64][72];   // [n][c], pitch 144 B
    const int n0 = blockIdx.x * 64, c0 = blockIdx.y * 64, bb = blockIdx.z;
    const int t = threadIdx.x;
    const int rc = t & 63;          // channel within tile
    const int g  = t >> 6;          // n-chunk group of 16
    const int c  = c0 + rc;
    const int bg = bb * NG + c / CPG;
    float s = 0.f, q = 0.f;
#pragma unroll
    for (int j = 0; j < 16; ++j) {
        s += partial[(bg * 16 + j) * 2];
        q += partial[(bg * 16 + j) * 2 + 1];
    }
    const float cnt = (float)(CPG * NSP);
    float mean = s / cnt;
    float var  = q / cnt - mean * mean;
    float rstd = rsqrtf(var + 1e-5f);
    float wf = w[c] * rstd, bv = b[c] - mean * wf;
    const float* px = x + ((size_t)bb * CH + c) * NSP + n0 + g * 16;
#pragma unroll
    for (int i = 0; i < 4; ++i) {
        float4 v = *(const float4*)(px + i * 4);
        T[g * 16 + i * 4 + 0][rc] = f2bf(v.x * wf + bv);
        T[g * 16 + i * 4 + 1][rc] = f2bf(v.y * wf + bv);
        T[g * 16 + i * 4 + 2][rc] = f2bf(v.z * wf + bv);
        T[g * 16 + i * 4 + 3][rc] = f2bf(v.w * wf + bv);
    }
    __syncthreads();
    int n = t >> 2, ch = (t & 3) * 16;
    uint4 o0 = *(const uint4*)&T[n][ch];
    uint4 o1 = *(const uint4*)&T[n][ch + 8];
    u16* dst = xnT + ((size_t)bb * NSP + n0 + n) * CH + c0 + ch;
    *(uint4*)dst = o0;
    *(uint4*)(dst + 8) = o1;
}

// ------- MFMA GEMM for QKV: Y[m][n] = sum_c Aw[m][c] * xnT[n][c] + bias[m] -------
__global__ __launch_bounds__(256) void gemm_qkv(const u16* __restrict__ Aw,
                                                const float* __restrict__ bias,
                                                const u16* __restrict__ xnT,
                                                u16* __restrict__ qT,
                                                u16* __restrict__ kT,
                                                u16* __restrict__ v) {
    const int n0 = blockIdx.x * 64, m0 = blockIdx.y * 64, bb = blockIdx.z;
    const int wave = threadIdx.x >> 6, lane = threadIdx.x & 63;
    const int lq = lane & 15, quad = lane >> 4;
    const int wm = (wave >> 1) * 32, wn = (wave & 1) * 32;
    f32x4 acc[2][2] = {};
    const u16* ap = Aw + (size_t)(m0 + wm + lq) * CH + quad * 8;
    const u16* bp = xnT + ((size_t)bb * NSP + n0 + wn + lq) * CH + quad * 8;
#pragma unroll
    for (int k0 = 0; k0 < CH; k0 += 32) {
        bf16x8 a0 = *(const bf16x8*)(ap + k0);
        bf16x8 a1 = *(const bf16x8*)(ap + 16 * CH + k0);
        bf16x8 b0 = *(const bf16x8*)(bp + k0);
        bf16x8 b1 = *(const bf16x8*)(bp + 16 * CH + k0);
        acc[0][0] = MFMA(a0, b0, acc[0][0], 0, 0, 0);
        acc[0][1] = MFMA(a0, b1, acc[0][1], 0, 0, 0);
        acc[1][0] = MFMA(a1, b0, acc[1][0], 0, 0, 0);
        acc[1][1] = MFMA(a1, b1, acc[1][1], 0, 0, 0);
    }
    const int sect = m0 >> 8;              // 0=Q, 1=K, 2=V
    const int h = (m0 & 255) >> 6;         // head for Q/K sections
#pragma unroll
    for (int im = 0; im < 2; ++im) {
        int ml = wm + im * 16 + quad * 4;  // +r, local m in [0,64)
        float4 bs = *(const float4*)(bias + m0 + ml);
#pragma unroll
        for (int in = 0; in < 2; ++in) {
            int n = n0 + wn + in * 16 + lq;
            f32x4 a = acc[im][in];
            float v0 = a[0] + bs.x, v1 = a[1] + bs.y;
            float v2 = a[2] + bs.z, v3 = a[3] + bs.w;
            if (sect < 2) {
                u16* base = (sect ? kT : qT) +
                            (((size_t)bb * NHD + h) * NSP + n) * HDIM + ml;
                ushort4 o;
                o.x = f2bf(v0); o.y = f2bf(v1); o.z = f2bf(v2); o.w = f2bf(v3);
                *(ushort4*)base = o;
            } else {
                u16* vb = v + ((size_t)bb * CH + (m0 - 512) + ml) * NSP + n;
                vb[0]        = f2bf(v0);
                vb[NSP]      = f2bf(v1);
                vb[2 * NSP]  = f2bf(v2);
                vb[3 * NSP]  = f2bf(v3);
            }
        }
    }
}

// ---------------- double-buffered LDS MFMA flash attention ----------------
// One block = 64 queries, 4 waves x 16 q, grid 512 = 2 independent blocks/CU
// (barrier decoupling). K/V tiles double-buffered in LDS -> ONE __syncthreads
// per iter; global prefetch issued a full compute-phase ahead. Inner math
// identical to verified attn4.
__global__ __launch_bounds__(256, 2) void attn5(const u16* __restrict__ qT,
                                                const u16* __restrict__ kT,
                                                const u16* __restrict__ vN,
                                                u16* __restrict__ aoT) {
    __shared__ u16 Ks[2][64][72];   // [buf][key][ch]
    __shared__ u16 Vs[2][64][72];   // [buf][ch][key]
    __shared__ u16 Ps[4][16][72];   // per-wave P round-trip
    const int h = blockIdx.y, bb = blockIdx.z;
    const int t = threadIdx.x;
    const int wave = t >> 6, lane = t & 63;
    const int lq = lane & 15, quad = lane >> 4;
    const int nq = blockIdx.x * 64 + wave * 16 + lq;     // this lane's query
    const u16* qp = qT + (((size_t)bb * NHD + h) * NSP + nq) * HDIM + quad * 8;
    bf16x8 q0 = *(const bf16x8*)qp;
    bf16x8 q1 = *(const bf16x8*)(qp + 32);
    const u16* kbase = kT + (((size_t)bb * NHD + h) * NSP) * (size_t)HDIM;
    const u16* vbase = vN + ((size_t)bb * CH + h * HDIM) * NSP;
    // staging: 256 threads, 64B each per array (2 uint4): row=t>>2, cols (t&3)*8, +32
    const int srow = t >> 2, scol = (t & 3) * 8;
    uint4 kr0 = *(const uint4*)(kbase + (size_t)srow * HDIM + scol);
    uint4 kr1 = *(const uint4*)(kbase + (size_t)srow * HDIM + scol + 32);
    uint4 vr0 = *(const uint4*)(vbase + (size_t)srow * NSP + scol);
    uint4 vr1 = *(const uint4*)(vbase + (size_t)srow * NSP + scol + 32);
    // write tile 0 into buf 0
    *(uint4*)&Ks[0][srow][scol]      = kr0;
    *(uint4*)&Ks[0][srow][scol + 32] = kr1;
    *(uint4*)&Vs[0][srow][scol]      = vr0;
    *(uint4*)&Vs[0][srow][scol + 32] = vr1;
    // start load of tile 1
    kr0 = *(const uint4*)(kbase + (size_t)(64 + srow) * HDIM + scol);
    kr1 = *(const uint4*)(kbase + (size_t)(64 + srow) * HDIM + scol + 32);
    vr0 = *(const uint4*)(vbase + (size_t)srow * NSP + 64 + scol);
    vr1 = *(const uint4*)(vbase + (size_t)srow * NSP + 64 + scol + 32);

    float m_r = -1e30f, l_r = 0.f;
    f32x4 O[4] = {{0.f,0.f,0.f,0.f},{0.f,0.f,0.f,0.f},
                  {0.f,0.f,0.f,0.f},{0.f,0.f,0.f,0.f}};
    for (int kt = 0; kt < 64; ++kt) {
        const int cur = kt & 1;
        __syncthreads();   // all waves done with iter kt-1 (reads of buf cur^1 done)
        if (kt < 63) {     // tile kt+1 regs -> buf cur^1 (loads issued last iter)
            *(uint4*)&Ks[cur ^ 1][srow][scol]      = kr0;
            *(uint4*)&Ks[cur ^ 1][srow][scol + 32] = kr1;
            *(uint4*)&Vs[cur ^ 1][srow][scol]      = vr0;
            *(uint4*)&Vs[cur ^ 1][srow][scol + 32] = vr1;
        }
        if (kt < 62) {     // issue load of tile kt+2 (lands during this compute)
            const int k2 = (kt + 2) * 64;
            kr0 = *(const uint4*)(kbase + (size_t)(k2 + srow) * HDIM + scol);
            kr1 = *(const uint4*)(kbase + (size_t)(k2 + srow) * HDIM + scol + 32);
            vr0 = *(const uint4*)(vbase + (size_t)srow * NSP + k2 + scol);
            vr1 = *(const uint4*)(vbase + (size_t)srow * NSP + k2 + scol + 32);
        }
        // S^T[key][q]: A-frag = Ks[key][ch-contig], B-frag = Q
        f32x4 st[4];
#pragma unroll
        for (int mt = 0; mt < 4; ++mt) {
            bf16x8 a0 = *(const bf16x8*)&Ks[cur][mt * 16 + lq][quad * 8];
            bf16x8 a1 = *(const bf16x8*)&Ks[cur][mt * 16 + lq][32 + quad * 8];
            f32x4 acc = {0.f, 0.f, 0.f, 0.f};
            acc = MFMA(a0, q0, acc, 0, 0, 0);
            acc = MFMA(a1, q1, acc, 0, 0, 0);
            st[mt] = acc * 0.125f;       // scale = hd^-0.5
        }
        // online softmax: lane's 16 scores all belong to query nq
        float mx = m_r;
#pragma unroll
        for (int mt = 0; mt < 4; ++mt)
#pragma unroll
            for (int r = 0; r < 4; ++r) mx = fmaxf(mx, st[mt][r]);
        mx = fmaxf(mx, __shfl_xor(mx, 16));
        mx = fmaxf(mx, __shfl_xor(mx, 32));
        float alpha = __expf(m_r - mx);
        m_r = mx;
        float sum = 0.f;
#pragma unroll
        for (int mt = 0; mt < 4; ++mt) {
            float p0 = __expf(st[mt][0] - mx);
            float p1 = __expf(st[mt][1] - mx);
            float p2 = __expf(st[mt][2] - mx);
            float p3 = __expf(st[mt][3] - mx);
            sum += p0 + p1 + p2 + p3;
            ushort4 pk;
            pk.x = f2bf(p0); pk.y = f2bf(p1); pk.z = f2bf(p2); pk.w = f2bf(p3);
            *(ushort4*)&Ps[wave][lq][mt * 16 + quad * 4] = pk;
        }
        sum += __shfl_xor(sum, 16);
        sum += __shfl_xor(sum, 32);
        l_r = l_r * alpha + sum;
        // PV: O[c][q] += V[c][key] * P^T[key][q]   (per-wave LDS ops in-order)
        bf16x8 p0 = *(const bf16x8*)&Ps[wave][lq][quad * 8];
        bf16x8 p1 = *(const bf16x8*)&Ps[wave][lq][32 + quad * 8];
#pragma unroll
        for (int mtc = 0; mtc < 4; ++mtc) {
            O[mtc] *= alpha;
            bf16x8 v0 = *(const bf16x8*)&Vs[cur][mtc * 16 + lq][quad * 8];
            bf16x8 v1 = *(const bf16x8*)&Vs[cur][mtc * 16 + lq][32 + quad * 8];
            O[mtc] = MFMA(v0, p0, O[mtc], 0, 0, 0);
            O[mtc] = MFMA(v1, p1, O[mtc], 0, 0, 0);
        }
    }
    float linv = 1.f / l_r;
    u16* op = aoT + ((size_t)bb * NSP + nq) * CH + h * HDIM;
#pragma unroll
    for (int mtc = 0; mtc < 4; ++mtc) {
        ushort4 o;
        o.x = f2bf(O[mtc][0] * linv);
        o.y = f2bf(O[mtc][1] * linv);
        o.z = f2bf(O[mtc][2] * linv);
        o.w = f2bf(O[mtc][3] * linv);
        *(ushort4*)(op + mtc * 16 + quad * 4) = o;
    }
}

// ------- MFMA GEMM proj: out[b][m][n] = sum_c Pw[m][c]*aoT[n][c] + bias + x -------
__global__ __launch_bounds__(256) void gemm_proj(const u16* __restrict__ Aw,
                                                 const float* __restrict__ bias,
                                                 const u16* __restrict__ aoT,
                                                 const float* __restrict__ xres,
                                                 float* __restrict__ out) {
    const int n0 = blockIdx.x * 64, m0 = blockIdx.y * 64, bb = blockIdx.z;
    const int wave = threadIdx.x >> 6, lane = threadIdx.x & 63;
    const int lq = lane & 15, quad = lane >> 4;
    const int wm = (wave >> 1) * 32, wn = (wave & 1) * 32;
    f32x4 acc[2][2] = {};
    const u16* ap = Aw + (size_t)(m0 + wm + lq) * CH + quad * 8;
    const u16* bp = aoT + ((size_t)bb * NSP + n0 + wn + lq) * CH + quad * 8;
#pragma unroll
    for (int k0 = 0; k0 < CH; k0 += 32) {
        bf16x8 a0 = *(const bf16x8*)(ap + k0);
        bf16x8 a1 = *(const bf16x8*)(ap + 16 * CH + k0);
        bf16x8 b0 = *(const bf16x8*)(bp + k0);
        bf16x8 b1 = *(const bf16x8*)(bp + 16 * CH + k0);
        acc[0][0] = MFMA(a0, b0, acc[0][0], 0, 0, 0);
        acc[0][1] = MFMA(a0, b1, acc[0][1], 0, 0, 0);
        acc[1][0] = MFMA(a1, b0, acc[1][0], 0, 0, 0);
        acc[1][1] = MFMA(a1, b1, acc[1][1], 0, 0, 0);
    }
#pragma unroll
    for (int im = 0; im < 2; ++im) {
        int ml = wm + im * 16 + quad * 4;
        float4 bs = *(const float4*)(bias + m0 + ml);
        float bsv[4] = {bs.x, bs.y, bs.z, bs.w};
#pragma unroll
        for (int in = 0; in < 2; ++in) {
            int n = n0 + wn + in * 16 + lq;
            f32x4 a = acc[im][in];
#pragma unroll
            for (int r = 0; r < 4; ++r) {
                size_t idx = ((size_t)bb * CH + m0 + ml + r) * NSP + n;
                out[idx] = a[r] + bsv[r] + xres[idx];
            }
        }
    }
}

extern "C" void kernel_launch(void* const* d_in, const int* in_sizes, int n_in,
                              void* d_out, int out_size, void* d_ws, size_t ws_size,
                              hipStream_t stream) {
    const float* x      = (const float*)d_in[0];
    const float* norm_w = (const float*)d_in[1];
    const float* norm_b = (const float*)d_in[2];
    const float* qkv_w  = (const float*)d_in[3];
    const float* qkv_b  = (const float*)d_in[4];
    const float* proj_w = (const float*)d_in[5];
    const float* proj_b = (const float*)d_in[6];
    float* out = (float*)d_out;

    char* w = (char*)d_ws;
    float* partial = (float*)w;                       // 4 KB (16x16x2 fp32)
    u16* wqb = (u16*)(w + 4096);                      // 384 KB (768x256 bf16)
    u16* wpb = (u16*)(w + 4096 + 393216);             // 128 KB (256x256 bf16)
    u16* xnT = (u16*)(w + 528384);                    // 4 MB [b][n][c] (aliased by aoT)
    u16* qT  = (u16*)(w + 528384 + 4194304);          // 4 MB [b][h][n][c]
    u16* kT  = (u16*)(w + 528384 + 2 * 4194304);      // 4 MB [b][h][n][c]
    u16* v   = (u16*)(w + 528384 + 3 * 4194304);      // 4 MB [b][c][n]
    u16* aoT = xnT;                                   // xnT dead after gemm_qkv

    wconv2<<<dim3(256), 256, 0, stream>>>(qkv_w, proj_w, wqb, wpb);
    gn_part<<<dim3(NB * NG, 16), 256, 0, stream>>>(x, partial);
    gn_apply_t<<<dim3(NSP / 64, CH / 64, NB), 256, 0, stream>>>(
        x, partial, norm_w, norm_b, xnT);
    gemm_qkv<<<dim3(NSP / 64, (3 * CH) / 64, NB), 256, 0, stream>>>(
        wqb, qkv_b, xnT, qT, kT, v);
    attn5<<<dim3(NSP / 64, NHD, NB), 256, 0, stream>>>(qT, kT, v, aoT);
    gemm_proj<<<dim3(NSP / 64, CH / 64, NB), 256, 0, stream>>>(
        wpb, proj_b, aoT, x, out);
}